// Round 7
// baseline (124.578 us; speedup 1.0000x reference)
//
#include <hip/hip_runtime.h>
#include <hip/hip_bf16.h>

// feature [B=128, E=64, D=128] fp32 -> N = 8192 rows of dim 128.
// loss = mean_r( log(den_r) - log(pos_r) ),
//   den_r = sum_c exp(10*<f_r,f_c>), pos_r = sum over c in r's 64-row block.
//
// v7 (resubmit; round-6 failure was container infra, not the kernel):
// global latency removed from the inner loop. Each block stages a 256-row
// B super-tile (64 KB) into LDS ONCE (swizzled global_load_lds, v1's verified
// pattern), then sweeps 4 A row-blocks against it. Inner loop = ds_read_b128
// (swizzle-corrected, conflict-free) + MFMA + exp2 only; ONE barrier total.
// MFMA pipe/SIMD = 2 waves x 4 rb x 128 mfma x 19.4cyc = 19.9K cyc ~ 8.3us
// floor -> MFMA-bound by construction. A frags (only remaining global loads,
// 16/rb) are prefetched for rb+1 before the flush shuffles/atomics.
#define N_ROWS 8192
#define DIM    128
#define TILE   128
#define BCOLS  256   // B super-tile rows (output cols) per block
#define RPB    4     // A row-blocks swept per block
#define EXPTEN 22026.465794806718f  // exp(10.0)
// Xb = normalize(f) * SCALE, SCALE^2 = 10*log2(e); then exp2(dot) = exp(10*<f,f>)
#define SCALE  3.7982826f

typedef __attribute__((ext_vector_type(8))) short short8;   // 8 bf16 = 4 VGPRs
typedef __attribute__((ext_vector_type(4))) float floatx4;  // MFMA C/D

#define EXP2F(x) __builtin_amdgcn_exp2f(x)

// async global->LDS DMA, 16B per lane; LDS dest = uniform base + lane*16
#define GLOAD_LDS(g, l)                                                        \
    __builtin_amdgcn_global_load_lds(                                          \
        (const __attribute__((address_space(1))) void*)(g),                    \
        (__attribute__((address_space(3))) void*)(l), 16, 0, 0)

// ---- Kernel 1: L2-normalize rows, scale, cast to bf16; zero pos/den ----
__global__ void norm_kernel(const float* __restrict__ F, __hip_bfloat16* __restrict__ Xb,
                            float* __restrict__ pos, float* __restrict__ den) {
    int lane = threadIdx.x & 63;
    int wave = threadIdx.x >> 6;
    int row  = blockIdx.x * 4 + wave;           // 2048 blocks x 4 waves = 8192 rows
    const float2 v = *(const float2*)(F + (size_t)row * DIM + lane * 2);
    float ss = v.x * v.x + v.y * v.y;
    #pragma unroll
    for (int m = 1; m < 64; m <<= 1) ss += __shfl_xor(ss, m);
    float inv = rsqrtf(ss) * SCALE;
    __hip_bfloat162 o;
    o.x = __float2bfloat16(v.x * inv);
    o.y = __float2bfloat16(v.y * inv);
    *((__hip_bfloat162*)(Xb + (size_t)row * DIM) + lane) = o;
    if (lane == 0) { pos[row] = 0.f; den[row] = 0.f; }
}

// ---- Kernel 2: fused gram + exp + row sums; B-supertile resident in LDS ----
// Block (rbg, cg): A rows [rbg*512, +512) x B cols [cg*256, +256).
// 4 waves 2x2 (wm,wn): wave-tile 64 rows x 128 cols per rb.
// LDS chunk j holds global 16B-chunk (j&15)^(r&15) of row j>>4 (XOR swizzle
// folded into the global source so ds_read_b128 is bank-conflict-free).
__global__ __launch_bounds__(256, 2) void gram_kernel(
        const __hip_bfloat16* __restrict__ Xb,
        float* __restrict__ pos, float* __restrict__ den) {
    __shared__ __hip_bfloat16 Bs[BCOLS * DIM];   // 64 KB
    const int tid  = threadIdx.x;
    const int rbg  = blockIdx.x;      // 0..15
    const int cg   = blockIdx.y;      // 0..31
    const int lane = tid & 63;
    const int wave = tid >> 6;
    const int wm   = wave >> 1, wn = wave & 1;
    const int quad = lane >> 4;       // 0..3
    const int l15  = lane & 15;       // 0..15

    // ---- one-time stage: 4096 16B-chunks, 16 issues/thread, swizzled src ----
    #pragma unroll
    for (int it = 0; it < 16; ++it) {
        int chunk = (it * 4 + wave) * 64 + lane;
        int r  = chunk >> 4;                      // 0..255
        int cs = (chunk & 15) ^ (r & 15);
        const __hip_bfloat16* gp = Xb + ((size_t)(cg * BCOLS + r)) * DIM + cs * 8;
        char* lp = (char*)&Bs[0] + (it * 4 + wave) * 1024;   // wave-uniform base
        GLOAD_LDS(gp, lp);
    }

    // A fragments for the first rb (loads overlap the stage; barrier drains both)
    short8 af[4][4];
    {
        const int rb = rbg * RPB;
        const __hip_bfloat16* Ab = Xb + ((size_t)(rb * TILE + wm * 64 + l15)) * DIM + quad * 8;
        #pragma unroll
        for (int mi = 0; mi < 4; ++mi)
            #pragma unroll
            for (int ko = 0; ko < 4; ++ko)
                af[mi][ko] = *(const short8*)(Ab + mi * 16 * DIM + ko * 32);
    }
    __syncthreads();   // the ONLY barrier: B stage + A loads complete

    // this wave's 128 LDS rows (cols cg*256 + wn*128 ..+128)
    const char* Bw = (const char*)&Bs[0] + (size_t)wn * 128 * 256;

    #pragma unroll 1
    for (int rbi = 0; rbi < RPB; ++rbi) {
        const int rb = rbg * RPB + rbi;
        // E-block of this wave's rows: ER = rb*2+wm; its pos cols live in this
        // wave's range iff dlt = ER - (cg*4 + wn*2) is 0 or 1 (ni half = dlt).
        const int dlt = (rb * 2 + wm) - (cg * 4 + wn * 2);
        const bool has_pos = (dlt == 0) || (dlt == 1);

        float dp[4][4], pp[4][4];
        #pragma unroll
        for (int a = 0; a < 4; ++a)
            #pragma unroll
            for (int b = 0; b < 4; ++b) { dp[a][b] = 0.f; pp[a][b] = 0.f; }

        #pragma unroll
        for (int ni = 0; ni < 8; ++ni) {
            short8 bf[4];
            #pragma unroll
            for (int ko = 0; ko < 4; ++ko) {
                int r  = ni * 16 + l15;              // row within wave's half
                int ch = (ko * 4 + quad) ^ l15;      // undo staging swizzle
                bf[ko] = *(const short8*)(Bw + r * 256 + ch * 16);
            }
            floatx4 acc[4];
            #pragma unroll
            for (int mi = 0; mi < 4; ++mi) acc[mi] = (floatx4)0.0f;
            #pragma unroll
            for (int ko = 0; ko < 4; ++ko)
                #pragma unroll
                for (int mi = 0; mi < 4; ++mi)
                    acc[mi] = __builtin_amdgcn_mfma_f32_16x16x32_bf16(
                        af[mi][ko], bf[ko], acc[mi], 0, 0, 0);

            const bool posni = has_pos && ((ni >> 2) == dlt);
            const int  nl    = ni & 3;
            #pragma unroll
            for (int mi = 0; mi < 4; ++mi)
                #pragma unroll
                for (int rg = 0; rg < 4; ++rg) {
                    float ex = EXP2F(acc[mi][rg]);
                    // diagonal: replace bf16-noisy exp(10*||x||^2) with exact exp(10)
                    if (posni && nl == mi && l15 == quad * 4 + rg)
                        ex = EXPTEN;
                    dp[mi][rg] += ex;
                    if (posni) pp[mi][rg] += ex;
                }
        }

        // prefetch next rb's A fragments before the flush (covers load latency)
        if (rbi + 1 < RPB) {
            const __hip_bfloat16* Ab =
                Xb + ((size_t)((rb + 1) * TILE + wm * 64 + l15)) * DIM + quad * 8;
            #pragma unroll
            for (int mi = 0; mi < 4; ++mi)
                #pragma unroll
                for (int ko = 0; ko < 4; ++ko)
                    af[mi][ko] = *(const short8*)(Ab + mi * 16 * DIM + ko * 32);
        }

        // flush den (+pos) for this rb: 16-lane shfl reduce, 1 atomic per row
        #pragma unroll
        for (int mi = 0; mi < 4; ++mi)
            #pragma unroll
            for (int rg = 0; rg < 4; ++rg) {
                float d = dp[mi][rg];
                #pragma unroll
                for (int m = 1; m < 16; m <<= 1) d += __shfl_xor(d, m);
                if (l15 == 0)
                    atomicAdd(&den[rb * TILE + wm * 64 + mi * 16 + quad * 4 + rg], d);
            }
        if (has_pos) {
            #pragma unroll
            for (int mi = 0; mi < 4; ++mi)
                #pragma unroll
                for (int rg = 0; rg < 4; ++rg) {
                    float p = pp[mi][rg];
                    #pragma unroll
                    for (int m = 1; m < 16; m <<= 1) p += __shfl_xor(p, m);
                    if (l15 == 0)
                        atomicAdd(&pos[rb * TILE + wm * 64 + mi * 16 + quad * 4 + rg], p);
                }
        }
    }
}

// ---- Kernel 3: loss = mean(log(den/pos)) ----
__global__ void loss_kernel(const float* __restrict__ pos, const float* __restrict__ den,
                            float* __restrict__ out) {
    __shared__ float red[4];
    float acc = 0.f;
    for (int i = threadIdx.x; i < N_ROWS / 4; i += 256) {
        float4 d = ((const float4*)den)[i];
        float4 p = ((const float4*)pos)[i];
        acc += __logf(d.x / p.x) + __logf(d.y / p.y) +
               __logf(d.z / p.z) + __logf(d.w / p.w);
    }
    #pragma unroll
    for (int m = 1; m < 64; m <<= 1) acc += __shfl_xor(acc, m);
    int lane = threadIdx.x & 63, w = threadIdx.x >> 6;
    if (lane == 0) red[w] = acc;
    __syncthreads();
    if (threadIdx.x == 0)
        out[0] = (red[0] + red[1] + red[2] + red[3]) * (1.0f / (float)N_ROWS);
}

extern "C" void kernel_launch(void* const* d_in, const int* in_sizes, int n_in,
                              void* d_out, int out_size, void* d_ws, size_t ws_size,
                              hipStream_t stream) {
    const float* feature = (const float*)d_in[0];
    // ws layout: pos[8192] f32 | den[8192] f32 | Xb[8192*128] bf16
    float* pos = (float*)d_ws;
    float* den = pos + N_ROWS;
    __hip_bfloat16* Xb = (__hip_bfloat16*)(den + N_ROWS);

    norm_kernel<<<N_ROWS / 4, 256, 0, stream>>>(feature, Xb, pos, den);
    gram_kernel<<<dim3(N_ROWS / TILE / RPB, N_ROWS / BCOLS), 256, 0, stream>>>(Xb, pos, den);
    loss_kernel<<<1, 256, 0, stream>>>(pos, den, (float*)d_out);
}